// Round 3
// baseline (716.257 us; speedup 1.0000x reference)
//
#include <hip/hip_runtime.h>
#include <hip/hip_bf16.h>

// Problem constants
#define IMG   224
#define PS    16
#define GDIM  14      // IMG/PS
#define NPATCH 196    // GDIM*GDIM
#define CIN   3
#define NCOUT 768
#define NB    64      // batch
#define KDIM  768     // CIN*PS*PS

// Tiling
#define BK    32
#define BN    128
#define LDA   40      // padded LDS row stride in bf16 (80 B = 5x16B, conflict ~2-way)
#define NITER (KDIM / BK)   // 24

using short8  = __attribute__((ext_vector_type(8))) short;
using floatx4 = __attribute__((ext_vector_type(4))) float;

// Pack float4 -> 4 bf16 (RNE) as uint2 for one 8B LDS store.
static __device__ __forceinline__ uint2 pk4(float4 v) {
    __hip_bfloat162 lo = __float22bfloat162_rn(make_float2(v.x, v.y));
    __hip_bfloat162 hi = __float22bfloat162_rn(make_float2(v.z, v.w));
    uint2 r;
    r.x = *reinterpret_cast<unsigned int*>(&lo);
    r.y = *reinterpret_cast<unsigned int*>(&hi);
    return r;
}

// GEMM per (patch, o-tile): C[64,128] = A[64,768] * W[p, o0:o0+128, :]^T + bias
// Double-buffered LDS, BK=32, ONE barrier per K-iter; next chunk's global
// loads are issued after the barrier so their latency overlaps ds_read+MFMA.
__global__ __launch_bounds__(256)
void dynconv_gemm(const float* __restrict__ x,
                  const float* __restrict__ W,
                  const float* __restrict__ bias,
                  __hip_bfloat16* __restrict__ ws,
                  float* __restrict__ out,
                  int use_ws) {
    __shared__ __align__(16) short As[2][NB][LDA];   // 2 x 64 x 32 chunk
    __shared__ __align__(16) short Bs[2][BN][LDA];   // 2 x 128 x 32 chunk

    const int tid = threadIdx.x;

    // XCD-swizzled block mapping: id = (p>>3)*48 + no*8 + (p&7).
    // All 6 o-blocks of a patch share id%8 -> same XCD (L2 reuse of x-patch).
    const int id  = blockIdx.x;
    const int pg  = id / 48;
    const int rm  = id % 48;
    const int no  = rm >> 3;
    const int p   = pg * 8 + (rm & 7);
    if (p >= NPATCH) return;
    const int o0  = no * BN;

    const int gi = p / GDIM;
    const int gj = p % GDIM;

    const int lane = tid & 63;
    const int wv   = tid >> 6;        // 0..3, wave id
    const int row  = lane & 15;
    const int quad = lane >> 4;       // 0..3

    floatx4 acc[4][2] = {};           // 4 m-tiles x 2 n-tiles per wave

    // Staging mapping: 8 threads cover 32 k (float4 each), 32 threads cover rows
    const int c2   = (tid & 7) << 2;  // k column in chunk: 0..28 step 4
    const int rowb = tid >> 3;        // 0..31

    const float* Wp = W + ((size_t)p * NCOUT + o0) * KDIM;

    float4 ra[2];     // A prefetch regs (2 x 32 rows)
    float4 rbv[4];    // B prefetch regs (4 x 32 rows)

    auto loadA = [&](int kk) {
        const int kg  = kk + c2;
        const int ch  = kg >> 8;          // channel
        const int rem = kg & 255;
        const int rowoff = (gi * PS + (rem >> 4)) * IMG + gj * PS + (rem & 15);
        #pragma unroll
        for (int i = 0; i < 2; ++i) {
            const int m = rowb + (i << 5);
            ra[i] = *(const float4*)(x + (size_t)(m * CIN + ch) * (IMG * IMG) + rowoff);
        }
    };
    auto loadB = [&](int kk) {
        const float* wsrc = Wp + kk + c2;
        #pragma unroll
        for (int i = 0; i < 4; ++i)
            rbv[i] = *(const float4*)(wsrc + (size_t)(rowb + (i << 5)) * KDIM);
    };
    auto storeLDS = [&](int buf) {
        #pragma unroll
        for (int i = 0; i < 2; ++i)
            *(uint2*)&As[buf][rowb + (i << 5)][c2] = pk4(ra[i]);
        #pragma unroll
        for (int i = 0; i < 4; ++i)
            *(uint2*)&Bs[buf][rowb + (i << 5)][c2] = pk4(rbv[i]);
    };

    // Prologue: fetch chunk 0 and stage into buffer 0.
    loadA(0);
    loadB(0);
    storeLDS(0);

    for (int it = 0; it < NITER; ++it) {
        const int cur = it & 1;
        const int nxt = cur ^ 1;
        const bool more = (it + 1) < NITER;

        __syncthreads();   // buf[cur] stores visible; prev readers of buf[nxt] done

        // Issue next chunk's global loads NOW (after barrier) so HBM latency
        // overlaps the ds_read + MFMA phase below; the vmcnt wait lands at
        // the storeLDS, not at a barrier.
        if (more) {
            loadA((it + 1) * BK);
            loadB((it + 1) * BK);
        }

        // MFMA over buf[cur] (one 16x16x32 k-step)
        {
            short8 a[4], bf[2];
            const int kofs = quad * 8;
            #pragma unroll
            for (int mt = 0; mt < 4; ++mt)
                a[mt] = *(const short8*)&As[cur][mt * 16 + row][kofs];
            #pragma unroll
            for (int nt = 0; nt < 2; ++nt)
                bf[nt] = *(const short8*)&Bs[cur][wv * 32 + nt * 16 + row][kofs];
            #pragma unroll
            for (int mt = 0; mt < 4; ++mt)
                #pragma unroll
                for (int nt = 0; nt < 2; ++nt)
                    acc[mt][nt] = __builtin_amdgcn_mfma_f32_16x16x32_bf16(
                        a[mt], bf[nt], acc[mt][nt], 0, 0, 0);
        }

        // Stage next chunk into the other buffer (no barrier needed: readers
        // of buf[nxt] finished before this iteration's barrier).
        if (more)
            storeLDS(nxt);
    }

    // ---- epilogue: bias + store ----
    // C/D layout: row m = quad*4 + reg, col n = lane&15  (per 16x16 tile)
    #pragma unroll
    for (int mt = 0; mt < 4; ++mt) {
        #pragma unroll
        for (int nt = 0; nt < 2; ++nt) {
            const int n = wv * 32 + nt * 16 + row;
            const int o = o0 + n;
            const float bv = bias[p * NCOUT + o];
            #pragma unroll
            for (int r = 0; r < 4; ++r) {
                const int m = mt * 16 + quad * 4 + r;
                const float val = acc[mt][nt][r] + bv;
                if (use_ws) {
                    // bf16 [b][p][o] layout: coalesced over o
                    ws[((size_t)m * NPATCH + p) * NCOUT + o] = __float2bfloat16(val);
                } else {
                    // direct fp32 [b][o][p] layout: scattered (fallback)
                    out[((size_t)m * NCOUT + o) * NPATCH + p] = val;
                }
            }
        }
    }
}

// Transpose ws bf16 [b][p][o] -> out fp32 [b][o][p], 32(p) x 64(o) LDS tiles.
__global__ __launch_bounds__(256)
void dynconv_transpose(const __hip_bfloat16* __restrict__ ws,
                       float* __restrict__ out) {
    __shared__ float tile[32][65];    // [p][o], pad 65 -> conflict-free
    const int b  = blockIdx.z;
    const int p0 = blockIdx.x * 32;
    const int o0 = blockIdx.y * 64;
    const int tid = threadIdx.x;

    // Read phase: 32 lanes cover 64 o via bf16x2; 8 p-rows per pass.
    {
        const int cc = tid & 31;          // o-pair index
        const int rr = tid >> 5;          // 0..7
        #pragma unroll
        for (int i = 0; i < 4; ++i) {
            const int pr = p0 + rr + i * 8;
            if (pr < NPATCH) {
                const __hip_bfloat162 v = *(const __hip_bfloat162*)
                    &ws[((size_t)b * NPATCH + pr) * NCOUT + o0 + 2 * cc];
                tile[rr + i * 8][2 * cc]     = __bfloat162float(v.x);
                tile[rr + i * 8][2 * cc + 1] = __bfloat162float(v.y);
            }
        }
    }
    __syncthreads();
    // Write phase: 32 lanes cover 32 p (contiguous); 8 o-rows per pass.
    {
        const int c = tid & 31;           // p offset
        const int r = tid >> 5;           // 0..7
        const int pc = p0 + c;
        if (pc < NPATCH) {
            #pragma unroll
            for (int i = 0; i < 8; ++i) {
                const int orow = o0 + r + i * 8;
                out[((size_t)b * NCOUT + orow) * NPATCH + pc] = tile[c][r + i * 8];
            }
        }
    }
}

extern "C" void kernel_launch(void* const* d_in, const int* in_sizes, int n_in,
                              void* d_out, int out_size, void* d_ws, size_t ws_size,
                              hipStream_t stream) {
    const float* x    = (const float*)d_in[0];
    const float* W    = (const float*)d_in[1];
    const float* bias = (const float*)d_in[2];
    float* out = (float*)d_out;

    const size_t need = (size_t)NB * NPATCH * NCOUT * sizeof(__hip_bfloat16); // 19.3 MB
    const int use_ws = (d_ws != nullptr && ws_size >= need) ? 1 : 0;
    __hip_bfloat16* ws = (__hip_bfloat16*)d_ws;

    // Grid 1200 = 25 groups x 48 (8 patches x 6 o-tiles); 24 blocks early-exit.
    dynconv_gemm<<<dim3(1200), dim3(256), 0, stream>>>(
        x, W, bias, ws, out, use_ws);

    if (use_ws) {
        dynconv_transpose<<<dim3(7, 12, 64), dim3(256), 0, stream>>>(ws, out);
    }
}